// Round 4
// baseline (321.965 us; speedup 1.0000x reference)
//
#include <hip/hip_runtime.h>
#include <math.h>

// DisCo (distance correlation) for N=8192, scalar output. 2 kernels + 1 memset:
//   K1 k_pass1 (512x4): partial weighted row sums of |ai-aj|,|bi-bj| -> pa,pb[4][N].
//       Last-done block (atomic counter): assemble avg rows, grand means (double),
//       write adja[j]=avga[j]-ga/2, adjb[j]=avgb[j]-gb/2.
//   K2 k_pass2 (512x4): centered row sums S_AB,S_AA,S_BB partials -> pAB/pAA/pBB.
//       Last-done block: assemble full rows, abs(S_AB)*w, double reduce,
//       power branch, NaN/clamp -> out[0].
// Fixup blocks use fixed-order reductions over fixed data -> deterministic
// regardless of WHICH block runs them. Counters zeroed per call via memsetAsync.

#define NN 8192
#define BLK 256
#define RPT 4                           // rows per thread
#define ROWS_PER_BLOCK 16               // 4 waves x RPT (waves share columns)
#define GRIDX 512                       // NN / ROWS_PER_BLOCK
#define CSPLIT 4                        // column segments
#define SEGC 2048                       // NN / CSPLIT
#define ITERS 8                         // SEGC / (64 lanes * 4 floats)
#define NBLK (GRIDX * CSPLIT)           // 2048

// ---------------------------------------------------------------- helpers
__device__ __forceinline__ void p1_elem(
    float aj, float bj, float wj,
    const float* __restrict__ ai, const float* __restrict__ bi,
    float* __restrict__ sa, float* __restrict__ sb) {
#pragma unroll
  for (int m = 0; m < RPT; ++m) {
    sa[m] = fmaf(fabsf(ai[m] - aj), wj, sa[m]);
    sb[m] = fmaf(fabsf(bi[m] - bj), wj, sb[m]);
  }
}

__device__ __forceinline__ void p2_elem(
    float aj, float bj, float wj, float caj, float cbj,
    const float* __restrict__ ai, const float* __restrict__ bi,
    const float* __restrict__ ra, const float* __restrict__ rb,
    float* __restrict__ sAB, float* __restrict__ sAA, float* __restrict__ sBB) {
#pragma unroll
  for (int m = 0; m < RPT; ++m) {
    const float A = (fabsf(ai[m] - aj) - ra[m]) - caj;
    const float B = (fabsf(bi[m] - bj) - rb[m]) - cbj;
    const float Aw = A * wj;
    const float Bw = B * wj;
    sAB[m] = fmaf(Aw, B, sAB[m]);
    sAA[m] = fmaf(Aw, A, sAA[m]);
    sBB[m] = fmaf(Bw, B, sBB[m]);
  }
}

// -------------------------------------------- K1: pass 1 + centering fixup
__global__ __launch_bounds__(BLK) void k_pass1(
    const float* __restrict__ a, const float* __restrict__ b,
    const float* __restrict__ w,
    float* __restrict__ pa, float* __restrict__ pb,
    float* __restrict__ adja, float* __restrict__ adjb,
    unsigned* __restrict__ cnt) {
  const int lane = threadIdx.x & 63;
  const int wv = threadIdx.x >> 6;
  const int i0 = blockIdx.x * ROWS_PER_BLOCK + wv * RPT;
  const int seg = blockIdx.y;

  {
    float ai[RPT], bi[RPT], sa[RPT], sb[RPT];
#pragma unroll
    for (int m = 0; m < RPT; ++m) {
      ai[m] = a[i0 + m]; bi[m] = b[i0 + m];
      sa[m] = 0.f; sb[m] = 0.f;
    }

    const int jb = seg * SEGC;
    const float4* a4 = (const float4*)(a + jb) + lane;
    const float4* b4 = (const float4*)(b + jb) + lane;
    const float4* w4 = (const float4*)(w + jb) + lane;

    float4 A0 = a4[0], B0 = b4[0], W0 = w4[0];
#pragma unroll 1
    for (int k = 0; k < ITERS - 1; ++k) {
      const int nx = (k + 1) * 64;
      const float4 A1 = a4[nx], B1 = b4[nx], W1 = w4[nx];
      p1_elem(A0.x, B0.x, W0.x, ai, bi, sa, sb);
      p1_elem(A0.y, B0.y, W0.y, ai, bi, sa, sb);
      p1_elem(A0.z, B0.z, W0.z, ai, bi, sa, sb);
      p1_elem(A0.w, B0.w, W0.w, ai, bi, sa, sb);
      A0 = A1; B0 = B1; W0 = W1;
    }
    p1_elem(A0.x, B0.x, W0.x, ai, bi, sa, sb);
    p1_elem(A0.y, B0.y, W0.y, ai, bi, sa, sb);
    p1_elem(A0.z, B0.z, W0.z, ai, bi, sa, sb);
    p1_elem(A0.w, B0.w, W0.w, ai, bi, sa, sb);

#pragma unroll
    for (int off = 32; off >= 1; off >>= 1) {
#pragma unroll
      for (int m = 0; m < RPT; ++m) {
        sa[m] += __shfl_xor(sa[m], off);
        sb[m] += __shfl_xor(sb[m], off);
      }
    }
    if (lane == 0) {
#pragma unroll
      for (int m = 0; m < RPT; ++m) {
        pa[seg * NN + i0 + m] = sa[m];
        pb[seg * NN + i0 + m] = sb[m];
      }
    }
  }

  // ---- last-done-block fixup: assemble avg, grand means, write adj arrays
  __threadfence();
  __shared__ int amLast;
  if (threadIdx.x == 0) amLast = (atomicAdd(cnt, 1u) == NBLK - 1);
  __syncthreads();
  if (!amLast) return;
  __threadfence();

  double da = 0.0, db = 0.0;
  for (int k = 0; k < NN / BLK; ++k) {
    const int i = k * BLK + threadIdx.x;
    const float av = (pa[i] + pa[NN + i] + pa[2 * NN + i] + pa[3 * NN + i]) * (1.0f / NN);
    const float bv = (pb[i] + pb[NN + i] + pb[2 * NN + i] + pb[3 * NN + i]) * (1.0f / NN);
    adja[i] = av; adjb[i] = bv;          // temp: raw avg (same thread rewrites below)
    da += (double)av * (double)w[i];
    db += (double)bv * (double)w[i];
  }
#pragma unroll
  for (int off = 32; off >= 1; off >>= 1) {
    da += __shfl_xor(da, off);
    db += __shfl_xor(db, off);
  }
  __shared__ double lda[4], ldb[4];
  __shared__ float hh[2];
  if (lane == 0) { lda[wv] = da; ldb[wv] = db; }
  __syncthreads();
  if (threadIdx.x == 0) {
    const double ga = lda[0] + lda[1] + lda[2] + lda[3];
    const double gb = ldb[0] + ldb[1] + ldb[2] + ldb[3];
    hh[0] = (float)(0.5 * ga / NN);      // ga/2
    hh[1] = (float)(0.5 * gb / NN);
  }
  __syncthreads();
  const float ha = hh[0], hb = hh[1];
  for (int k = 0; k < NN / BLK; ++k) {
    const int i = k * BLK + threadIdx.x;   // same i-mapping as loop above
    adja[i] -= ha;                          // adj = avg - g/2
    adjb[i] -= hb;
  }
}

// ------------------------------------------- K2: pass 2 + tail/final fixup
__global__ __launch_bounds__(BLK) void k_pass2(
    const float* __restrict__ a, const float* __restrict__ b,
    const float* __restrict__ w,
    const float* __restrict__ adja, const float* __restrict__ adjb,
    float* __restrict__ pAB, float* __restrict__ pAA, float* __restrict__ pBB,
    const int* __restrict__ powerPtr, float* __restrict__ out,
    unsigned* __restrict__ cnt) {
  const int lane = threadIdx.x & 63;
  const int wv = threadIdx.x >> 6;
  const int i0 = blockIdx.x * ROWS_PER_BLOCK + wv * RPT;
  const int seg = blockIdx.y;

  {
    float ai[RPT], bi[RPT], ra[RPT], rb[RPT];
    float sAB[RPT], sAA[RPT], sBB[RPT];
#pragma unroll
    for (int m = 0; m < RPT; ++m) {
      ai[m] = a[i0 + m]; bi[m] = b[i0 + m];
      ra[m] = adja[i0 + m];   // already centered: adj_i
      rb[m] = adjb[i0 + m];
      sAB[m] = 0.f; sAA[m] = 0.f; sBB[m] = 0.f;
    }

    const int jb = seg * SEGC;
    const float4* a4  = (const float4*)(a + jb)    + lane;
    const float4* b4  = (const float4*)(b + jb)    + lane;
    const float4* w4  = (const float4*)(w + jb)    + lane;
    const float4* ca4 = (const float4*)(adja + jb) + lane;
    const float4* cb4 = (const float4*)(adjb + jb) + lane;

    float4 A0 = a4[0], B0 = b4[0], W0 = w4[0], CA0 = ca4[0], CB0 = cb4[0];
#pragma unroll 1
    for (int k = 0; k < ITERS - 1; ++k) {
      const int nx = (k + 1) * 64;
      const float4 A1 = a4[nx], B1 = b4[nx], W1 = w4[nx], CA1 = ca4[nx], CB1 = cb4[nx];
      p2_elem(A0.x, B0.x, W0.x, CA0.x, CB0.x, ai, bi, ra, rb, sAB, sAA, sBB);
      p2_elem(A0.y, B0.y, W0.y, CA0.y, CB0.y, ai, bi, ra, rb, sAB, sAA, sBB);
      p2_elem(A0.z, B0.z, W0.z, CA0.z, CB0.z, ai, bi, ra, rb, sAB, sAA, sBB);
      p2_elem(A0.w, B0.w, W0.w, CA0.w, CB0.w, ai, bi, ra, rb, sAB, sAA, sBB);
      A0 = A1; B0 = B1; W0 = W1; CA0 = CA1; CB0 = CB1;
    }
    p2_elem(A0.x, B0.x, W0.x, CA0.x, CB0.x, ai, bi, ra, rb, sAB, sAA, sBB);
    p2_elem(A0.y, B0.y, W0.y, CA0.y, CB0.y, ai, bi, ra, rb, sAB, sAA, sBB);
    p2_elem(A0.z, B0.z, W0.z, CA0.z, CB0.z, ai, bi, ra, rb, sAB, sAA, sBB);
    p2_elem(A0.w, B0.w, W0.w, CA0.w, CB0.w, ai, bi, ra, rb, sAB, sAA, sBB);

#pragma unroll
    for (int off = 32; off >= 1; off >>= 1) {
#pragma unroll
      for (int m = 0; m < RPT; ++m) {
        sAB[m] += __shfl_xor(sAB[m], off);
        sAA[m] += __shfl_xor(sAA[m], off);
        sBB[m] += __shfl_xor(sBB[m], off);
      }
    }
    if (lane == 0) {
#pragma unroll
      for (int m = 0; m < RPT; ++m) {
        pAB[seg * NN + i0 + m] = sAB[m];
        pAA[seg * NN + i0 + m] = sAA[m];
        pBB[seg * NN + i0 + m] = sBB[m];
      }
    }
  }

  // ---- last-done-block fixup: assemble rows, abs+weight, final scalar
  __threadfence();
  __shared__ int amLast;
  if (threadIdx.x == 0) amLast = (atomicAdd(cnt, 1u) == NBLK - 1);
  __syncthreads();
  if (!amLast) return;
  __threadfence();

  double ab = 0.0, aa = 0.0, bb = 0.0;
  for (int k = 0; k < NN / BLK; ++k) {
    const int i = k * BLK + threadIdx.x;
    const float sab = pAB[i] + pAB[NN + i] + pAB[2 * NN + i] + pAB[3 * NN + i];
    const float saa = pAA[i] + pAA[NN + i] + pAA[2 * NN + i] + pAA[3 * NN + i];
    const float sbb = pBB[i] + pBB[NN + i] + pBB[2 * NN + i] + pBB[3 * NN + i];
    const float wi = w[i];
    ab += (double)(fabsf(sab) * wi);    // abs of complete row sum
    aa += (double)(saa * wi);
    bb += (double)(sbb * wi);
  }
#pragma unroll
  for (int off = 32; off >= 1; off >>= 1) {
    ab += __shfl_xor(ab, off);
    aa += __shfl_xor(aa, off);
    bb += __shfl_xor(bb, off);
  }
  __shared__ double l[3][4];
  if (lane == 0) { l[0][wv] = ab; l[1][wv] = aa; l[2][wv] = bb; }
  __syncthreads();
  if (threadIdx.x == 0) {
    const double n2 = (double)NN * (double)NN;
    const double num = (l[0][0] + l[0][1] + l[0][2] + l[0][3]) / n2;
    const double mAA = (l[1][0] + l[1][1] + l[1][2] + l[1][3]) / n2;
    const double mBB = (l[2][0] + l[2][1] + l[2][2] + l[2][3]) / n2;
    const double den = fabs(mAA * mBB);
    const int p = powerPtr[0];
    double d;
    if (p == 1) {
      d = num / sqrt(den + 1e-12);
    } else if (p == 2) {
      d = (num * num) / (den + 1e-12);
    } else {
      d = pow(num / sqrt(mAA * mBB) + 1e-12, (double)p);
    }
    if (isnan(d)) d = 0.0;
    if (d < 0.0) d = 0.0;
    out[0] = (float)d;
  }
}

// -------------------------------------------------------------------- launcher
extern "C" void kernel_launch(void* const* d_in, const int* in_sizes, int n_in,
                              void* d_out, int out_size, void* d_ws, size_t ws_size,
                              hipStream_t stream) {
  const float* a = (const float*)d_in[0];
  const float* b = (const float*)d_in[1];
  const float* w = (const float*)d_in[2];
  const int* power = (const int*)d_in[3];
  float* out = (float*)d_out;

  float* ws = (float*)d_ws;
  float* pa   = ws;                  // [4N]
  float* pb   = pa + 4 * NN;         // [4N]
  float* pAB  = pb + 4 * NN;         // [4N]
  float* pAA  = pAB + 4 * NN;        // [4N]
  float* pBB  = pAA + 4 * NN;        // [4N]
  float* adja = pBB + 4 * NN;        // [N]
  float* adjb = adja + NN;           // [N]
  unsigned* cnt = (unsigned*)(adjb + NN);   // [2], 4B-aligned

  hipMemsetAsync(cnt, 0, 2 * sizeof(unsigned), stream);

  const dim3 grid(GRIDX, CSPLIT);
  k_pass1<<<grid, BLK, 0, stream>>>(a, b, w, pa, pb, adja, adjb, &cnt[0]);
  k_pass2<<<grid, BLK, 0, stream>>>(a, b, w, adja, adjb, pAB, pAA, pBB,
                                    power, out, &cnt[1]);
}

// Round 5
// 45.480 us; speedup vs baseline: 7.0792x; 7.0792x over previous
//
#include <hip/hip_runtime.h>
#include <math.h>

// DisCo (distance correlation) for N=8192, scalar output. 5 kernels, no fences.
// Algebraic expansion: A_ij = d_ij - r_i - r_j (d=|a_i-a_j|, r=avg-ga/2); all
// polynomial-in-(a_i-a_j) terms are O(N); only |.|-terms need pairwise sweeps.
//   K1 k_pass1 (512x4): partial row sums P0a=Σw|da|, P0b=Σw|db| per segment;
//                       per-block double partial of Σ_i w_i*rowsum_i (for ga).
//   K2 k_mid   (32):    ga,gb from 2048 partials; avg, r=avg-ga/2, s=avg_b-gb/2,
//                       wr=w*r, ws=w*s arrays; 10 O(N) scalars (dbl, per-block).
//   K3 k_pass2 (512x4): 5 pairwise sums/row: Q=Σw d e, P1a=Σ(wr)d, P2=Σ(ws)d,
//                       P3=Σ(wr)e, P1b=Σ(ws)e  (8 VALU/pair).
//   K4 k_tail  (32):    assemble T_AB/T_AA/T_BB per row from P*/scalars (dbl),
//                       |T_AB|*w_i etc., per-block double partials.
//   K5 k_fin   (1x64):  reduce 32 triples, power branch, NaN/clamp.
// All reductions fixed-order -> deterministic. NO per-block device fences
// (round-4 lesson: __threadfence per block cost ~+125us/kernel on gfx950).

#define NN 8192
#define BLK 256
#define RPT 4                           // rows per thread
#define ROWS_PER_BLOCK 16               // 4 waves x RPT (waves share columns)
#define GRIDX 512                       // NN / ROWS_PER_BLOCK
#define CSPLIT 4                        // column segments
#define SEGC 2048                       // NN / CSPLIT
#define ITERS 8                         // SEGC / (64 lanes * 4 floats)
#define NBLK (GRIDX * CSPLIT)           // 2048
#define MIDB 32                         // glue-kernel blocks
#define INV_N (1.0f / NN)

// ---------------------------------------------------------------- K1: pass 1
__device__ __forceinline__ void p1_elem(
    float aj, float bj, float wj,
    const float* __restrict__ ai, const float* __restrict__ bi,
    float* __restrict__ sa, float* __restrict__ sb) {
#pragma unroll
  for (int m = 0; m < RPT; ++m) {
    sa[m] = fmaf(fabsf(ai[m] - aj), wj, sa[m]);
    sb[m] = fmaf(fabsf(bi[m] - bj), wj, sb[m]);
  }
}

__global__ __launch_bounds__(BLK) void k_pass1(
    const float* __restrict__ a, const float* __restrict__ b,
    const float* __restrict__ w,
    float* __restrict__ pa, float* __restrict__ pb,
    double* __restrict__ gpa, double* __restrict__ gpb) {
  const int lane = threadIdx.x & 63;
  const int wv = threadIdx.x >> 6;
  const int i0 = blockIdx.x * ROWS_PER_BLOCK + wv * RPT;
  const int seg = blockIdx.y;

  float ai[RPT], bi[RPT], sa[RPT], sb[RPT];
#pragma unroll
  for (int m = 0; m < RPT; ++m) {
    ai[m] = a[i0 + m]; bi[m] = b[i0 + m];
    sa[m] = 0.f; sb[m] = 0.f;
  }

  const int jb = seg * SEGC;
  const float4* a4 = (const float4*)(a + jb) + lane;
  const float4* b4 = (const float4*)(b + jb) + lane;
  const float4* w4 = (const float4*)(w + jb) + lane;

  float4 A0 = a4[0], B0 = b4[0], W0 = w4[0];
#pragma unroll 1
  for (int k = 0; k < ITERS - 1; ++k) {
    const int nx = (k + 1) * 64;
    const float4 A1 = a4[nx], B1 = b4[nx], W1 = w4[nx];
    p1_elem(A0.x, B0.x, W0.x, ai, bi, sa, sb);
    p1_elem(A0.y, B0.y, W0.y, ai, bi, sa, sb);
    p1_elem(A0.z, B0.z, W0.z, ai, bi, sa, sb);
    p1_elem(A0.w, B0.w, W0.w, ai, bi, sa, sb);
    A0 = A1; B0 = B1; W0 = W1;
  }
  p1_elem(A0.x, B0.x, W0.x, ai, bi, sa, sb);
  p1_elem(A0.y, B0.y, W0.y, ai, bi, sa, sb);
  p1_elem(A0.z, B0.z, W0.z, ai, bi, sa, sb);
  p1_elem(A0.w, B0.w, W0.w, ai, bi, sa, sb);

#pragma unroll
  for (int off = 32; off >= 1; off >>= 1) {
#pragma unroll
    for (int m = 0; m < RPT; ++m) {
      sa[m] += __shfl_xor(sa[m], off);
      sb[m] += __shfl_xor(sb[m], off);
    }
  }

  __shared__ double gla[4], glb[4];
  if (lane == 0) {
#pragma unroll
    for (int m = 0; m < RPT; ++m) {
      pa[seg * NN + i0 + m] = sa[m];
      pb[seg * NN + i0 + m] = sb[m];
    }
    double da = 0.0, db = 0.0;
#pragma unroll
    for (int m = 0; m < RPT; ++m) {
      const double wi = (double)w[i0 + m];
      da += (double)sa[m] * wi;
      db += (double)sb[m] * wi;
    }
    gla[wv] = da; glb[wv] = db;
  }
  __syncthreads();
  if (threadIdx.x == 0) {
    const int bid = blockIdx.y * GRIDX + blockIdx.x;
    gpa[bid] = gla[0] + gla[1] + gla[2] + gla[3];
    gpb[bid] = glb[0] + glb[1] + glb[2] + glb[3];
  }
}

// ------------------------------------- K2: ga/gb, r/s/wr/ws arrays, scalars
__global__ __launch_bounds__(BLK) void k_mid(
    const float* __restrict__ a, const float* __restrict__ b,
    const float* __restrict__ w,
    const float* __restrict__ pa, const float* __restrict__ pb,
    const double* __restrict__ gpa, const double* __restrict__ gpb,
    float* __restrict__ avga, float* __restrict__ avgb,
    float* __restrict__ rr, float* __restrict__ ss,
    float* __restrict__ wr, float* __restrict__ ws,
    double* __restrict__ scal) {
  const int lane = threadIdx.x & 63;
  const int wv = threadIdx.x >> 6;

  __shared__ double gsum[2];
  if (wv < 2) {                 // wave0 -> ga partials, wave1 -> gb partials
    const double* g = wv ? gpb : gpa;
    double s = 0.0;
    for (int k = 0; k < NBLK / 64; ++k) s += g[lane + 64 * k];
#pragma unroll
    for (int off = 32; off >= 1; off >>= 1) s += __shfl_xor(s, off);
    if (lane == 0) gsum[wv] = s;
  }
  __syncthreads();
  const float ha = (float)(0.5 * gsum[0] / ((double)NN * (double)NN));  // ga/2
  const float hb = (float)(0.5 * gsum[1] / ((double)NN * (double)NN));  // gb/2

  const int i = blockIdx.x * BLK + threadIdx.x;   // MIDB*BLK == NN
  const float av = (pa[i] + pa[NN + i] + pa[2 * NN + i] + pa[3 * NN + i]) * INV_N;
  const float bv = (pb[i] + pb[NN + i] + pb[2 * NN + i] + pb[3 * NN + i]) * INV_N;
  const float ri = av - ha;
  const float si = bv - hb;
  const float wi = w[i], aiv = a[i], biv = b[i];
  avga[i] = av; avgb[i] = bv;
  rr[i] = ri;  ss[i] = si;
  wr[i] = wi * ri; ws[i] = wi * si;

  double p[10];
  p[0] = (double)wi;                       // W
  p[1] = (double)wi * aiv;                 // Ma1
  p[2] = (double)wi * aiv * aiv;           // Ma2
  p[3] = (double)wi * biv;                 // Mb1
  p[4] = (double)wi * biv * biv;           // Mb2
  p[5] = (double)wi * ri;                  // Swr
  p[6] = (double)wi * si;                  // Sws
  p[7] = (double)wi * ri * ri;             // Swr2
  p[8] = (double)wi * si * si;             // Sws2
  p[9] = (double)wi * ri * si;             // Swrs
#pragma unroll
  for (int off = 32; off >= 1; off >>= 1) {
#pragma unroll
    for (int t = 0; t < 10; ++t) p[t] += __shfl_xor(p[t], off);
  }
  __shared__ double lp[10][4];
  if (lane == 0) {
#pragma unroll
    for (int t = 0; t < 10; ++t) lp[t][wv] = p[t];
  }
  __syncthreads();
  if (threadIdx.x == 0) {
#pragma unroll
    for (int t = 0; t < 10; ++t)
      scal[t * MIDB + blockIdx.x] = lp[t][0] + lp[t][1] + lp[t][2] + lp[t][3];
  }
}

// --------------------------- K3: pass 2 — five pairwise sums, 8 VALU per pair
__global__ __launch_bounds__(BLK) void k_pass2(
    const float* __restrict__ a, const float* __restrict__ b,
    const float* __restrict__ w,
    const float* __restrict__ wr, const float* __restrict__ ws,
    float* __restrict__ Qp, float* __restrict__ P1a, float* __restrict__ P2,
    float* __restrict__ P3, float* __restrict__ P1b) {
  const int lane = threadIdx.x & 63;
  const int wv = threadIdx.x >> 6;
  const int i0 = blockIdx.x * ROWS_PER_BLOCK + wv * RPT;
  const int seg = blockIdx.y;

  float ai[RPT], bi[RPT];
  float q[RPT], g1a[RPT], g2[RPT], g3[RPT], g1b[RPT];
#pragma unroll
  for (int m = 0; m < RPT; ++m) {
    ai[m] = a[i0 + m]; bi[m] = b[i0 + m];
    q[m] = 0.f; g1a[m] = 0.f; g2[m] = 0.f; g3[m] = 0.f; g1b[m] = 0.f;
  }

  const int jb = seg * SEGC;
  const float4* a4 = (const float4*)(a + jb)  + lane;
  const float4* b4 = (const float4*)(b + jb)  + lane;
  const float4* w4 = (const float4*)(w + jb)  + lane;
  const float4* r4 = (const float4*)(wr + jb) + lane;
  const float4* s4 = (const float4*)(ws + jb) + lane;

#pragma unroll 1
  for (int k = 0; k < ITERS; ++k) {
    const int ix = k * 64;
    const float4 A = a4[ix], B = b4[ix], Wt = w4[ix], R = r4[ix], S = s4[ix];
#define P2E(e)                                            \
    {                                                     \
      _Pragma("unroll")                                   \
      for (int m = 0; m < RPT; ++m) {                     \
        const float dd = fabsf(ai[m] - A.e);              \
        const float ee = fabsf(bi[m] - B.e);              \
        g1a[m] = fmaf(R.e, dd, g1a[m]);                   \
        g2[m]  = fmaf(S.e, dd, g2[m]);                    \
        g3[m]  = fmaf(R.e, ee, g3[m]);                    \
        g1b[m] = fmaf(S.e, ee, g1b[m]);                   \
        q[m]   = fmaf(Wt.e * dd, ee, q[m]);               \
      }                                                   \
    }
    P2E(x) P2E(y) P2E(z) P2E(w)
#undef P2E
  }

#pragma unroll
  for (int off = 32; off >= 1; off >>= 1) {
#pragma unroll
    for (int m = 0; m < RPT; ++m) {
      q[m]   += __shfl_xor(q[m], off);
      g1a[m] += __shfl_xor(g1a[m], off);
      g2[m]  += __shfl_xor(g2[m], off);
      g3[m]  += __shfl_xor(g3[m], off);
      g1b[m] += __shfl_xor(g1b[m], off);
    }
  }
  if (lane == 0) {
#pragma unroll
    for (int m = 0; m < RPT; ++m) {
      const int o = seg * NN + i0 + m;
      Qp[o] = q[m]; P1a[o] = g1a[m]; P2[o] = g2[m];
      P3[o] = g3[m]; P1b[o] = g1b[m];
    }
  }
}

// --------------- K4: per-row T_AB/T_AA/T_BB assembly + per-block dbl partials
__global__ __launch_bounds__(BLK) void k_tail(
    const float* __restrict__ a, const float* __restrict__ b,
    const float* __restrict__ w,
    const float* __restrict__ avga, const float* __restrict__ avgb,
    const float* __restrict__ rr, const float* __restrict__ ss,
    const float* __restrict__ Qp, const float* __restrict__ P1a,
    const float* __restrict__ P2, const float* __restrict__ P3,
    const float* __restrict__ P1b,
    const double* __restrict__ scal,
    double* __restrict__ fAB, double* __restrict__ fAA, double* __restrict__ fBB) {
  const int lane = threadIdx.x & 63;
  const int wv = threadIdx.x >> 6;

  __shared__ double sc[10];
  if (threadIdx.x < 10) {
    double s = 0.0;
    for (int k = 0; k < MIDB; ++k) s += scal[threadIdx.x * MIDB + k];
    sc[threadIdx.x] = s;
  }
  __syncthreads();
  const double W   = sc[0], Ma1 = sc[1], Ma2 = sc[2], Mb1 = sc[3], Mb2 = sc[4];
  const double Swr = sc[5], Sws = sc[6], Swr2 = sc[7], Sws2 = sc[8], Swrs = sc[9];

  const int i = blockIdx.x * BLK + threadIdx.x;
  const double Qi   = (double)Qp[i]  + Qp[NN + i]  + Qp[2 * NN + i]  + Qp[3 * NN + i];
  const double P1ai = (double)P1a[i] + P1a[NN + i] + P1a[2 * NN + i] + P1a[3 * NN + i];
  const double P2i  = (double)P2[i]  + P2[NN + i]  + P2[2 * NN + i]  + P2[3 * NN + i];
  const double P3i  = (double)P3[i]  + P3[NN + i]  + P3[2 * NN + i]  + P3[3 * NN + i];
  const double P1bi = (double)P1b[i] + P1b[NN + i] + P1b[2 * NN + i] + P1b[3 * NN + i];
  const double av = avga[i], bv = avgb[i], ri = rr[i], si = ss[i];
  const double aiv = a[i], biv = b[i], wi = w[i];
  const double P0a = av * (double)NN;     // Σ_j w_j d_ij
  const double P0b = bv * (double)NN;

  const double TAB = Qi - si * P0a - P2i - ri * P0b - P3i
                   + ri * si * W + ri * Sws + si * Swr + Swrs;
  const double TAA = (aiv * aiv * W - 2.0 * aiv * Ma1 + Ma2)
                   - 2.0 * ri * P0a - 2.0 * P1ai
                   + ri * ri * W + 2.0 * ri * Swr + Swr2;
  const double TBB = (biv * biv * W - 2.0 * biv * Mb1 + Mb2)
                   - 2.0 * si * P0b - 2.0 * P1bi
                   + si * si * W + 2.0 * si * Sws + Sws2;

  double ab = fabs(TAB) * wi;
  double aa = TAA * wi;
  double bb = TBB * wi;
#pragma unroll
  for (int off = 32; off >= 1; off >>= 1) {
    ab += __shfl_xor(ab, off);
    aa += __shfl_xor(aa, off);
    bb += __shfl_xor(bb, off);
  }
  __shared__ double l[3][4];
  if (lane == 0) { l[0][wv] = ab; l[1][wv] = aa; l[2][wv] = bb; }
  __syncthreads();
  if (threadIdx.x == 0) {
    fAB[blockIdx.x] = l[0][0] + l[0][1] + l[0][2] + l[0][3];
    fAA[blockIdx.x] = l[1][0] + l[1][1] + l[1][2] + l[1][3];
    fBB[blockIdx.x] = l[2][0] + l[2][1] + l[2][2] + l[2][3];
  }
}

// ---------------------------------------------------------------- K5: finalize
__global__ __launch_bounds__(64) void k_fin(
    const double* __restrict__ fAB, const double* __restrict__ fAA,
    const double* __restrict__ fBB, const int* __restrict__ powerPtr,
    float* __restrict__ out) {
  const int lane = threadIdx.x;
  double ab = fAB[lane & (MIDB - 1)];
  double aa = fAA[lane & (MIDB - 1)];
  double bb = fBB[lane & (MIDB - 1)];
#pragma unroll
  for (int off = 16; off >= 1; off >>= 1) {
    ab += __shfl_xor(ab, off);
    aa += __shfl_xor(aa, off);
    bb += __shfl_xor(bb, off);
  }
  if (lane == 0) {
    const double n2 = (double)NN * (double)NN;
    const double num = ab / n2;
    const double mAA = aa / n2;
    const double mBB = bb / n2;
    const double den = fabs(mAA * mBB);
    const int p = powerPtr[0];
    double d;
    if (p == 1) {
      d = num / sqrt(den + 1e-12);
    } else if (p == 2) {
      d = (num * num) / (den + 1e-12);
    } else {
      d = pow(num / sqrt(mAA * mBB) + 1e-12, (double)p);
    }
    if (isnan(d)) d = 0.0;
    if (d < 0.0) d = 0.0;
    out[0] = (float)d;
  }
}

// -------------------------------------------------------------------- launcher
extern "C" void kernel_launch(void* const* d_in, const int* in_sizes, int n_in,
                              void* d_out, int out_size, void* d_ws, size_t ws_size,
                              hipStream_t stream) {
  const float* a = (const float*)d_in[0];
  const float* b = (const float*)d_in[1];
  const float* w = (const float*)d_in[2];
  const int* power = (const int*)d_in[3];
  float* out = (float*)d_out;

  float* ws = (float*)d_ws;
  float* pa   = ws;                  // [4N]
  float* pb   = pa  + 4 * NN;        // [4N]
  float* Qp   = pb  + 4 * NN;        // [4N]
  float* P1a  = Qp  + 4 * NN;        // [4N]
  float* P2   = P1a + 4 * NN;        // [4N]
  float* P3   = P2  + 4 * NN;        // [4N]
  float* P1b  = P3  + 4 * NN;        // [4N]
  float* avga = P1b + 4 * NN;        // [N]
  float* avgb = avga + NN;           // [N]
  float* rr   = avgb + NN;           // [N]
  float* ss   = rr + NN;             // [N]
  float* wrv  = ss + NN;             // [N]
  float* wsv  = wrv + NN;            // [N]  (34N floats total, 8B-aligned end)
  double* gpa  = (double*)(wsv + NN);   // [2048]
  double* gpb  = gpa + NBLK;            // [2048]
  double* scal = gpb + NBLK;            // [10*32]
  double* fAB  = scal + 10 * MIDB;      // [32]
  double* fAA  = fAB + MIDB;            // [32]
  double* fBB  = fAA + MIDB;            // [32]

  const dim3 grid(GRIDX, CSPLIT);
  k_pass1<<<grid, BLK, 0, stream>>>(a, b, w, pa, pb, gpa, gpb);
  k_mid<<<MIDB, BLK, 0, stream>>>(a, b, w, pa, pb, gpa, gpb,
                                  avga, avgb, rr, ss, wrv, wsv, scal);
  k_pass2<<<grid, BLK, 0, stream>>>(a, b, w, wrv, wsv, Qp, P1a, P2, P3, P1b);
  k_tail<<<MIDB, BLK, 0, stream>>>(a, b, w, avga, avgb, rr, ss,
                                   Qp, P1a, P2, P3, P1b, scal, fAB, fAA, fBB);
  k_fin<<<1, 64, 0, stream>>>(fAB, fAA, fBB, power, out);
}